// Round 14
// baseline (546.312 us; speedup 1.0000x reference)
//
#include <hip/hip_runtime.h>
#include <hip/hip_bf16.h>

// Binary tree LSTM. R14: logits DE-FUSED from GEMMs (ablation of the
// per-block epilogue tail). GEMM epilogue = gates + c/h stores only.
// All levels' h persist (hA + hRest arena reusing dead embB region);
// one final logits_all kernel (134 MB read, no atomics) computes out.
// Mid GEMMs: 128x(NG*GW) tile, 4 waves, 2 blocks/CU, counted-vmcnt
// 2-tile pipeline, same-XCD col-block grouping (R13).

#define HID 256

typedef __attribute__((ext_vector_type(8))) short short8;
typedef __attribute__((ext_vector_type(4))) float f32x4;
typedef __attribute__((ext_vector_type(4))) unsigned short ushort4v;

__device__ __forceinline__ float rcpf(float x) { return __builtin_amdgcn_rcpf(x); }
__device__ __forceinline__ float sigf(float x) { return rcpf(1.0f + __expf(-x)); }
__device__ __forceinline__ float tanhf_(float x) { return 2.0f * rcpf(1.0f + __expf(-2.0f * x)) - 1.0f; }
__device__ __forceinline__ float bf2f(unsigned short u) {
    union { unsigned int i; float f; } v; v.i = ((unsigned int)u) << 16; return v.f;
}
__device__ __forceinline__ unsigned short f2bf(float f) {
    __hip_bfloat16 b = __float2bfloat16(f);
    return *(unsigned short*)&b;
}
__device__ __forceinline__ void gload_lds16(const void* g, void* l) {
    __builtin_amdgcn_global_load_lds(
        (const __attribute__((address_space(1))) unsigned int*)g,
        (__attribute__((address_space(3))) unsigned int*)l, 16, 0, 0);
}
template <int N> __device__ __forceinline__ void waitcnt_vm() {
    if constexpr (N == 0)       asm volatile("s_waitcnt vmcnt(0)" ::: "memory");
    else if constexpr (N == 9)  asm volatile("s_waitcnt vmcnt(9)" ::: "memory");
    else if constexpr (N == 10) asm volatile("s_waitcnt vmcnt(10)" ::: "memory");
    else                        asm volatile("s_waitcnt vmcnt(0)" ::: "memory");
}

// ================= MID kernel: 128 rows, 4 waves (2M x 2N) =================
// 1D grid, same-XCD decomposition:
//   xcd = bid&7, slot = bid>>3, cb = slot%NCB, row0 = ((slot/NCB)*8+xcd)*128
// level: NG=5 FG=1 GW=32 NCB=8 | leaf: NG=3 FG=2 GW=64 NCB=4.
template <int NG, int FG, int NCB, int K, bool LEAF>
__global__ __launch_bounds__(256, 2) void gemm_mid(
    const unsigned short* __restrict__ A,
    const unsigned short* __restrict__ BT,
    const float* __restrict__ bias,     // (NG x 256)
    const float* __restrict__ cprev,    // (M x 512) f32, level only
    float* __restrict__ cout,
    unsigned short* __restrict__ hout)
{
    constexpr int CW   = FG * 16;
    constexpr int GW   = 2 * CW;
    constexpr int BN   = NG * GW;        // 160 level / 192 leaf
    constexpr int NK   = K / 64;
    constexpr int NBW  = BN / 32;        // 5 / 6
    constexpr int L    = 4 + NBW;        // 9 / 10
    constexpr int NF   = NG * FG;        // 5 / 6
    constexpr int ABUF = 128 * 128;
    constexpr int BBUF = BN * 128;
    constexpr int BUF  = ABUF + BBUF;

    __shared__ char smem[2 * BUF];       // 72 KB level, 80 KB leaf

    const int t = threadIdx.x;
    const int lane = t & 63;
    const int w = t >> 6;
    const int wm = w >> 1, wn = w & 1;

    const int bid = blockIdx.x;
    const int xcd = bid & 7;
    const int slot = bid >> 3;
    const int cb = slot % NCB;
    const int row0 = ((slot / NCB) * 8 + xcd) * 128;

    const int l3 = lane >> 3;
    const unsigned int swsrc = (unsigned int)(((lane & 7) ^ l3) * 16);
    unsigned int a_src[4];
    unsigned int b_src[NBW];
#pragma unroll
    for (int q = 0; q < 4; ++q)
        a_src[q] = (unsigned int)(row0 + (w * 4 + q) * 8 + l3) * (K * 2) + swsrc;
#pragma unroll
    for (int q = 0; q < NBW; ++q)
        b_src[q] = (unsigned int)(cb * BN + (w * NBW + q) * 8 + l3) * (K * 2) + swsrc;

    const int swz0 = ((lane >> 4) ^ (lane & 7)) * 16;
    const int swz1 = (((lane >> 4) + 4) ^ (lane & 7)) * 16;
    const int aoff = (wm * 64 + (lane & 15)) * 128;
    const int boff = (wn * CW + (lane & 15)) * 128;

    f32x4 acc[4][NF] = {};

    auto STAGE = [&](int buf, int kt) {
        char* As = smem + buf * BUF;
        char* Bs = As + ABUF;
        const unsigned int k0b = (unsigned int)kt * 128;
#pragma unroll
        for (int q = 0; q < 4; ++q)
            gload_lds16((const char*)A + (size_t)(a_src[q] + k0b),
                        As + (w * 4 + q) * 1024);
#pragma unroll
        for (int q = 0; q < NBW; ++q)
            gload_lds16((const char*)BT + (size_t)(b_src[q] + k0b),
                        Bs + (w * NBW + q) * 1024);
    };

    STAGE(0, 0);
    STAGE(1, 1);

#pragma unroll
    for (int kt = 0; kt < NK; ++kt) {
        const int cur = kt & 1;
        if (kt + 1 < NK) waitcnt_vm<L>(); else waitcnt_vm<0>();
        __builtin_amdgcn_s_barrier();
        const char* As = smem + cur * BUF;
        const char* Bs = As + ABUF;
#pragma unroll
        for (int ks = 0; ks < 2; ++ks) {
            const int sw = ks ? swz1 : swz0;
            short8 a[4], b[NF];
#pragma unroll
            for (int mf = 0; mf < 4; ++mf)
                a[mf] = *(const short8*)(As + aoff + mf * 2048 + sw);
#pragma unroll
            for (int g = 0; g < NG; ++g)
#pragma unroll
                for (int fc = 0; fc < FG; ++fc)
                    b[g * FG + fc] = *(const short8*)(Bs + g * (GW * 128) +
                                                      fc * 2048 + boff + sw);
            __builtin_amdgcn_s_setprio(1);
#pragma unroll
            for (int f = 0; f < NF; ++f)
#pragma unroll
                for (int mf = 0; mf < 4; ++mf)
                    acc[mf][f] = __builtin_amdgcn_mfma_f32_16x16x32_bf16(
                        a[mf], b[f], acc[mf][f], 0, 0, 0);
            __builtin_amdgcn_s_setprio(0);
        }
        asm volatile("s_waitcnt lgkmcnt(0)" ::: "memory");
        __builtin_amdgcn_sched_barrier(0);
        __builtin_amdgcn_s_barrier();
        if (kt + 2 < NK) STAGE(cur, kt + 2);
    }

    // ---- epilogue: gates + c/h stores only (logits de-fused) ----
#pragma unroll
    for (int mf = 0; mf < 4; ++mf) {
#pragma unroll
        for (int j = 0; j < 4; ++j) {
            const int rl = wm * 64 + mf * 16 + ((lane >> 4) << 2) + j;
            const int r = row0 + rl;
#pragma unroll
            for (int fc = 0; fc < FG; ++fc) {
                const int cl = wn * CW + fc * 16 + (lane & 15);
                const int c = cb * GW + cl;
                float cv, hv;
                if constexpr (LEAF) {
                    float p0 = acc[mf][0 * FG + fc][j] + bias[c];          // i
                    float p1 = acc[mf][1 * FG + fc][j] + bias[256 + c];    // o
                    float p2 = acc[mf][2 * FG + fc][j] + bias[512 + c];    // u
                    cv = sigf(p0) * tanhf_(p2);
                    hv = sigf(p1) * sigf(cv);   // reference: o * sig(c)
                } else {
                    float p0 = acc[mf][0 * FG + fc][j] + bias[c];           // inp
                    float p1 = acc[mf][1 * FG + fc][j] + bias[256 + c];     // fol
                    float p2 = acc[mf][2 * FG + fc][j] + bias[512 + c];     // for
                    float p3 = acc[mf][3 * FG + fc][j] + bias[768 + c];     // out
                    float p4 = acc[mf][4 * FG + fc][j] + bias[1024 + c];    // upd
                    float lc = cprev[(size_t)r * 512 + c];
                    float rc = cprev[(size_t)r * 512 + 256 + c];
                    cv = sigf(p0) * tanhf_(p4) + sigf(p1) * lc + sigf(p2) * rc;
                    hv = sigf(p3) * tanhf_(cv);
                }
                cout[(size_t)r * 256 + c] = cv;
                hout[(size_t)r * 256 + c] = f2bf(hv);
            }
        }
    }
}

// ================= SMALL kernel (tail levels): 128 rows, 4 waves ==========
template <int NG, int K>
__global__ __launch_bounds__(256, 3) void gemm_small(
    const unsigned short* __restrict__ A,
    const unsigned short* __restrict__ BT,
    const float* __restrict__ bias,
    const float* __restrict__ cprev,
    float* __restrict__ cout,
    unsigned short* __restrict__ hout)
{
    constexpr int CS  = 32;
    constexpr int BN  = NG * CS;
    constexpr int NK  = K / 64;
    constexpr int NBW = BN / 32;
    constexpr int ABUF = 128 * 128;

    __shared__ char smem[2 * ABUF + BN * 128];
    char* Bs = smem + 2 * ABUF;

    const int t = threadIdx.x;
    const int lane = t & 63;
    const int w = t >> 6;
    const int wm = w >> 1, wn = w & 1;
    const int cb = blockIdx.x;
    const int row0 = blockIdx.y * 128;

    const int l3 = lane >> 3;
    const unsigned int swsrc = (unsigned int)(((lane & 7) ^ l3) * 16);
    unsigned int a_src[4];
    unsigned int b_src[NBW];
#pragma unroll
    for (int q = 0; q < 4; ++q)
        a_src[q] = (unsigned int)(row0 + (w * 4 + q) * 8 + l3) * (K * 2) + swsrc;
#pragma unroll
    for (int q = 0; q < NBW; ++q)
        b_src[q] = (unsigned int)(cb * BN + (w * NBW + q) * 8 + l3) * (K * 2) + swsrc;

    const int swz0 = ((lane >> 4) ^ (lane & 7)) * 16;
    const int swz1 = (((lane >> 4) + 4) ^ (lane & 7)) * 16;
    const int aoff = (wm * 64 + (lane & 15)) * 128;
    const int boff = (wn * 16 + (lane & 15)) * 128;

    f32x4 acc[4][NG] = {};

    auto STAGE_A = [&](int buf, int kt) {
        char* As = smem + buf * ABUF;
        const unsigned int k0b = (unsigned int)kt * 128;
#pragma unroll
        for (int q = 0; q < 4; ++q)
            gload_lds16((const char*)A + (size_t)(a_src[q] + k0b),
                        As + (w * 4 + q) * 1024);
    };
    auto STAGE_B = [&](int kt) {
        const unsigned int k0b = (unsigned int)kt * 128;
#pragma unroll
        for (int q = 0; q < NBW; ++q)
            gload_lds16((const char*)BT + (size_t)(b_src[q] + k0b),
                        Bs + (w * NBW + q) * 1024);
    };

    STAGE_A(0, 0);
    STAGE_B(0);
    asm volatile("s_waitcnt vmcnt(0)" ::: "memory");
    __builtin_amdgcn_s_barrier();
    asm volatile("" ::: "memory");

#pragma unroll
    for (int kt = 0; kt < NK; ++kt) {
        const int cur = kt & 1;
        if (kt + 1 < NK) STAGE_A(cur ^ 1, kt + 1);
        const char* As = smem + cur * ABUF;
#pragma unroll
        for (int ks = 0; ks < 2; ++ks) {
            const int sw = ks ? swz1 : swz0;
            short8 a[4];
#pragma unroll
            for (int mf = 0; mf < 4; ++mf)
                a[mf] = *(const short8*)(As + aoff + mf * 2048 + sw);
#pragma unroll
            for (int g = 0; g < NG; ++g) {
                short8 b = *(const short8*)(Bs + g * (CS * 128) + boff + sw);
#pragma unroll
                for (int mf = 0; mf < 4; ++mf)
                    acc[mf][g] = __builtin_amdgcn_mfma_f32_16x16x32_bf16(
                        a[mf], b, acc[mf][g], 0, 0, 0);
            }
        }
        asm volatile("" ::: "memory");
        __builtin_amdgcn_s_barrier();
        asm volatile("" ::: "memory");
        if (kt + 1 < NK) {
            STAGE_B(kt + 1);
            asm volatile("s_waitcnt vmcnt(0)" ::: "memory");
        }
        __builtin_amdgcn_s_barrier();
        asm volatile("" ::: "memory");
    }

#pragma unroll
    for (int mf = 0; mf < 4; ++mf) {
#pragma unroll
        for (int j = 0; j < 4; ++j) {
            const int rl = wm * 64 + mf * 16 + ((lane >> 4) << 2) + j;
            const int r = row0 + rl;
            const int cl = wn * 16 + (lane & 15);
            const int c = cb * 32 + cl;
            float p0 = acc[mf][0][j] + bias[c];
            float p1 = acc[mf][1][j] + bias[256 + c];
            float p2 = acc[mf][2][j] + bias[512 + c];
            float p3 = acc[mf][3][j] + bias[768 + c];
            float p4 = acc[mf][4][j] + bias[1024 + c];
            float lc = cprev[(size_t)r * 512 + c];
            float rc = cprev[(size_t)r * 512 + 256 + c];
            float cv = sigf(p0) * tanhf_(p4) + sigf(p1) * lc + sigf(p2) * rc;
            float hv = sigf(p3) * tanhf_(cv);
            cout[(size_t)r * 256 + c] = cv;
            hout[(size_t)r * 256 + c] = f2bf(hv);
        }
    }
}

// ================= logits over ALL levels, one pass =================
// Row arena: R in [0,131072) -> hA; R in [131072, 261632) -> hRest.
// Level decode: V = 262144-R; lev = 17 - (31-clz(V-1)); start = 262144 - 2^(18-lev).
__global__ __launch_bounds__(256) void logits_all(
    const unsigned short* __restrict__ hA,
    const unsigned short* __restrict__ hRest,
    const float* __restrict__ W_out, const float* __restrict__ b_out,
    float* __restrict__ out)
{
    __shared__ float Ws[HID * 5];
    __shared__ float bs[5];
    const int t = threadIdx.x;
    for (int i = t; i < HID * 5; i += 256) Ws[i] = W_out[i];
    if (t < 5) bs[t] = b_out[t];
    __syncthreads();

    const int part = t & 15;
    const int rl = t >> 4;
    const int R = blockIdx.x * 16 + rl;   // [0, 261632)

    const unsigned short* h = (R < 131072)
        ? hA + (size_t)R * HID
        : hRest + (size_t)(R - 131072) * HID;

    float a0 = 0.f, a1 = 0.f, a2 = 0.f, a3 = 0.f, a4 = 0.f;
#pragma unroll
    for (int i = 0; i < 2; ++i) {
        short8 hv = *(const short8*)(h + part * 16 + i * 8);
#pragma unroll
        for (int e = 0; e < 8; ++e) {
            float f = bf2f((unsigned short)hv[e]);
            int c = part * 16 + i * 8 + e;
            a0 = fmaf(f, Ws[c * 5 + 0], a0);
            a1 = fmaf(f, Ws[c * 5 + 1], a1);
            a2 = fmaf(f, Ws[c * 5 + 2], a2);
            a3 = fmaf(f, Ws[c * 5 + 3], a3);
            a4 = fmaf(f, Ws[c * 5 + 4], a4);
        }
    }
#pragma unroll
    for (int m = 8; m >= 1; m >>= 1) {
        a0 += __shfl_xor(a0, m);
        a1 += __shfl_xor(a1, m);
        a2 += __shfl_xor(a2, m);
        a3 += __shfl_xor(a3, m);
        a4 += __shfl_xor(a4, m);
    }
    if (part == 0) {
        unsigned int V = 262144u - (unsigned int)R;
        int lev = 17 - (31 - __clz(V - 1));
        int start = 262144 - (1 << (18 - lev));
        int local = R - start;
        int nb = 8 - lev;
        int b = local >> nb, j = local & ((1 << nb) - 1);
        int off = 512 - (1 << (9 - lev));
        size_t o = ((size_t)b * 511 + off + j) * 5;
        out[o + 0] = a0 + bs[0];
        out[o + 1] = a1 + bs[1];
        out[o + 2] = a2 + bs[2];
        out[o + 3] = a3 + bs[3];
        out[o + 4] = a4 + bs[4];
    }
}

// ================= weight prep =================
__global__ __launch_bounds__(256) void prep_weights(
    const float* __restrict__ W_leaf, const float* __restrict__ W_nl,
    const float* __restrict__ b_nl,
    unsigned short* __restrict__ BleafT,   // leaf: colp = cb*192 + g*64 + cl(64)
    unsigned short* __restrict__ BlevT,    // level: colp = cb*160 + g*32 + cl(32)
    float* __restrict__ bb)
{
    const int T1 = 768 * 320, T2 = 1280 * 512, T3 = 5 * 256;
    for (int idx = blockIdx.x * 256 + threadIdx.x; idx < T1 + T2 + T3;
         idx += gridDim.x * 256) {
        if (idx < T1) {
            int colp = idx / 320, k = idx % 320;
            int cbv = colp / 192, rem = colp % 192;
            int g = rem >> 6, cl = rem & 63;
            int c = cbv * 64 + cl;
            float v = (k < 300) ? W_leaf[((size_t)g * 300 + k) * 256 + c] : 0.0f;
            BleafT[(size_t)colp * 320 + k] = f2bf(v);
        } else if (idx < T1 + T2) {
            int i2 = idx - T1;
            int colp = i2 / 512, k = i2 % 512;
            int cb8 = colp / 160, rem = colp % 160;
            int g = rem >> 5, cl = rem & 31;
            int c = cb8 * 32 + cl;
            float v = W_nl[((size_t)(2 * g + (k >= 256)) * 256 + (k & 255)) * 256 + c];
            BlevT[(size_t)colp * 512 + k] = f2bf(v);
        } else {
            int i3 = idx - T1 - T2;  // g*256 + c
            bb[i3] = b_nl[(size_t)(i3 >> 8) * 512 + (i3 & 255)] +
                     b_nl[(size_t)(i3 >> 8) * 512 + 256 + (i3 & 255)];
        }
    }
}

// ================= emb -> bf16, pad 300 -> 320 =================
__global__ __launch_bounds__(256) void emb_to_bf16(
    const float* __restrict__ emb, unsigned short* __restrict__ embB)
{
    const int total = 131072 * 80;
    for (int idx = blockIdx.x * 256 + threadIdx.x; idx < total;
         idx += gridDim.x * 256) {
        int r = idx / 80, q = idx % 80;
        ushort4v o;
        if (q < 75) {
            const float4 v = *(const float4*)(emb + (size_t)r * 300 + q * 4);
            o.x = f2bf(v.x); o.y = f2bf(v.y); o.z = f2bf(v.z); o.w = f2bf(v.w);
        } else {
            o.x = 0; o.y = 0; o.z = 0; o.w = 0;
        }
        *(ushort4v*)(embB + (size_t)r * 320 + q * 4) = o;
    }
}

extern "C" void kernel_launch(void* const* d_in, const int* in_sizes, int n_in,
                              void* d_out, int out_size, void* d_ws, size_t ws_size,
                              hipStream_t stream) {
    const float* emb    = (const float*)d_in[0];
    const float* W_leaf = (const float*)d_in[1];
    const float* b_leaf = (const float*)d_in[2];
    const float* W_nl   = (const float*)d_in[3];
    const float* b_nl   = (const float*)d_in[4];
    const float* W_out  = (const float*)d_in[5];
    const float* b_out  = (const float*)d_in[6];
    float* out = (float*)d_out;

    // workspace layout (bytes)
    char* ws = (char*)d_ws;
    unsigned short* embB   = (unsigned short*)(ws);              // 83,886,080
    unsigned short* hRest  = (unsigned short*)(ws);              // reuses embB after leaf
                                                                 // (130560*256*2 = 66,846,720)
    unsigned short* BleafT = (unsigned short*)(ws + 83886080);   //    491,520
    unsigned short* BlevT  = (unsigned short*)(ws + 84377600);   //  1,310,720
    float*          bb     = (float*)(ws + 85688320);            //      5,120
    float*          cA     = (float*)(ws + 85693440);            // 134,217,728
    unsigned short* hA     = (unsigned short*)(ws + 219911168);  //  67,108,864
    float*          cB     = (float*)(ws + 287020032);           //  67,108,864

    prep_weights<<<1024, 256, 0, stream>>>(W_leaf, W_nl, b_nl, BleafT, BlevT, bb);
    emb_to_bf16<<<2048, 256, 0, stream>>>(emb, embB);

    // leaf: M = 131072, NG=3 FG=2 (GW=64), NCB=4, 1D grid 4096 blocks
    gemm_mid<3, 2, 4, 320, true><<<4096, 256, 0, stream>>>(
        embB, BleafT, b_leaf, nullptr, cA, hA);

    const unsigned short* hp = hA;
    const float* cp = cA;
    size_t hoff = 0;
    for (int lev = 1; lev <= 8; ++lev) {
        int n = 1 << (8 - lev);
        int M = 512 * n;
        float* cd = (lev & 1) ? cB : cA;
        unsigned short* hd = hRest + hoff;   // embB region (dead after leaf)
        if (M >= 16384) {
            gemm_mid<5, 1, 8, 512, false><<<(M / 128) * 8, 256, 0, stream>>>(
                hp, BlevT, bb, cp, cd, hd);
        } else {
            gemm_small<5, 512><<<dim3(8, M / 128), 256, 0, stream>>>(
                hp, BlevT, bb, cp, cd, hd);
        }
        cp = cd;
        hp = hd;
        hoff += (size_t)M * HID;
    }

    // final logits over all 261632 rows (16 rows per block)
    logits_all<<<261632 / 16, 256, 0, stream>>>(hA, hRest, W_out, b_out, out);
}

// Round 15
// 451.663 us; speedup vs baseline: 1.2096x; 1.2096x over previous
//
#include <hip/hip_runtime.h>
#include <hip/hip_bf16.h>

// Binary tree LSTM. R15: de-fused GEMMs (R14, best measured) + FAST
// logits_all: W_out in 80 registers/thread (no LDS, zero bank conflicts),
// short8 h reads, 16-lane shuffle reduce, grid-stride 2048 blocks.
// Mid GEMMs: 128x(NG*GW) tile, 4 waves, 2 blocks/CU, counted-vmcnt
// 2-tile pipeline, same-XCD col-block grouping (R13).

#define HID 256

typedef __attribute__((ext_vector_type(8))) short short8;
typedef __attribute__((ext_vector_type(4))) float f32x4;
typedef __attribute__((ext_vector_type(4))) unsigned short ushort4v;

__device__ __forceinline__ float rcpf(float x) { return __builtin_amdgcn_rcpf(x); }
__device__ __forceinline__ float sigf(float x) { return rcpf(1.0f + __expf(-x)); }
__device__ __forceinline__ float tanhf_(float x) { return 2.0f * rcpf(1.0f + __expf(-2.0f * x)) - 1.0f; }
__device__ __forceinline__ float bf2f(unsigned short u) {
    union { unsigned int i; float f; } v; v.i = ((unsigned int)u) << 16; return v.f;
}
__device__ __forceinline__ unsigned short f2bf(float f) {
    __hip_bfloat16 b = __float2bfloat16(f);
    return *(unsigned short*)&b;
}
__device__ __forceinline__ void gload_lds16(const void* g, void* l) {
    __builtin_amdgcn_global_load_lds(
        (const __attribute__((address_space(1))) unsigned int*)g,
        (__attribute__((address_space(3))) unsigned int*)l, 16, 0, 0);
}
template <int N> __device__ __forceinline__ void waitcnt_vm() {
    if constexpr (N == 0)       asm volatile("s_waitcnt vmcnt(0)" ::: "memory");
    else if constexpr (N == 9)  asm volatile("s_waitcnt vmcnt(9)" ::: "memory");
    else if constexpr (N == 10) asm volatile("s_waitcnt vmcnt(10)" ::: "memory");
    else                        asm volatile("s_waitcnt vmcnt(0)" ::: "memory");
}

// ================= MID kernel: 128 rows, 4 waves (2M x 2N) =================
// 1D grid, same-XCD decomposition:
//   xcd = bid&7, slot = bid>>3, cb = slot%NCB, row0 = ((slot/NCB)*8+xcd)*128
// level: NG=5 FG=1 GW=32 NCB=8 | leaf: NG=3 FG=2 GW=64 NCB=4.
template <int NG, int FG, int NCB, int K, bool LEAF>
__global__ __launch_bounds__(256, 2) void gemm_mid(
    const unsigned short* __restrict__ A,
    const unsigned short* __restrict__ BT,
    const float* __restrict__ bias,     // (NG x 256)
    const float* __restrict__ cprev,    // (M x 512) f32, level only
    float* __restrict__ cout,
    unsigned short* __restrict__ hout)
{
    constexpr int CW   = FG * 16;
    constexpr int GW   = 2 * CW;
    constexpr int BN   = NG * GW;        // 160 level / 192 leaf
    constexpr int NK   = K / 64;
    constexpr int NBW  = BN / 32;        // 5 / 6
    constexpr int L    = 4 + NBW;        // 9 / 10
    constexpr int NF   = NG * FG;        // 5 / 6
    constexpr int ABUF = 128 * 128;
    constexpr int BBUF = BN * 128;
    constexpr int BUF  = ABUF + BBUF;

    __shared__ char smem[2 * BUF];       // 72 KB level, 80 KB leaf

    const int t = threadIdx.x;
    const int lane = t & 63;
    const int w = t >> 6;
    const int wm = w >> 1, wn = w & 1;

    const int bid = blockIdx.x;
    const int xcd = bid & 7;
    const int slot = bid >> 3;
    const int cb = slot % NCB;
    const int row0 = ((slot / NCB) * 8 + xcd) * 128;

    const int l3 = lane >> 3;
    const unsigned int swsrc = (unsigned int)(((lane & 7) ^ l3) * 16);
    unsigned int a_src[4];
    unsigned int b_src[NBW];
#pragma unroll
    for (int q = 0; q < 4; ++q)
        a_src[q] = (unsigned int)(row0 + (w * 4 + q) * 8 + l3) * (K * 2) + swsrc;
#pragma unroll
    for (int q = 0; q < NBW; ++q)
        b_src[q] = (unsigned int)(cb * BN + (w * NBW + q) * 8 + l3) * (K * 2) + swsrc;

    const int swz0 = ((lane >> 4) ^ (lane & 7)) * 16;
    const int swz1 = (((lane >> 4) + 4) ^ (lane & 7)) * 16;
    const int aoff = (wm * 64 + (lane & 15)) * 128;
    const int boff = (wn * CW + (lane & 15)) * 128;

    f32x4 acc[4][NF] = {};

    auto STAGE = [&](int buf, int kt) {
        char* As = smem + buf * BUF;
        char* Bs = As + ABUF;
        const unsigned int k0b = (unsigned int)kt * 128;
#pragma unroll
        for (int q = 0; q < 4; ++q)
            gload_lds16((const char*)A + (size_t)(a_src[q] + k0b),
                        As + (w * 4 + q) * 1024);
#pragma unroll
        for (int q = 0; q < NBW; ++q)
            gload_lds16((const char*)BT + (size_t)(b_src[q] + k0b),
                        Bs + (w * NBW + q) * 1024);
    };

    STAGE(0, 0);
    STAGE(1, 1);

#pragma unroll
    for (int kt = 0; kt < NK; ++kt) {
        const int cur = kt & 1;
        if (kt + 1 < NK) waitcnt_vm<L>(); else waitcnt_vm<0>();
        __builtin_amdgcn_s_barrier();
        const char* As = smem + cur * BUF;
        const char* Bs = As + ABUF;
#pragma unroll
        for (int ks = 0; ks < 2; ++ks) {
            const int sw = ks ? swz1 : swz0;
            short8 a[4], b[NF];
#pragma unroll
            for (int mf = 0; mf < 4; ++mf)
                a[mf] = *(const short8*)(As + aoff + mf * 2048 + sw);
#pragma unroll
            for (int g = 0; g < NG; ++g)
#pragma unroll
                for (int fc = 0; fc < FG; ++fc)
                    b[g * FG + fc] = *(const short8*)(Bs + g * (GW * 128) +
                                                      fc * 2048 + boff + sw);
            __builtin_amdgcn_s_setprio(1);
#pragma unroll
            for (int f = 0; f < NF; ++f)
#pragma unroll
                for (int mf = 0; mf < 4; ++mf)
                    acc[mf][f] = __builtin_amdgcn_mfma_f32_16x16x32_bf16(
                        a[mf], b[f], acc[mf][f], 0, 0, 0);
            __builtin_amdgcn_s_setprio(0);
        }
        asm volatile("s_waitcnt lgkmcnt(0)" ::: "memory");
        __builtin_amdgcn_sched_barrier(0);
        __builtin_amdgcn_s_barrier();
        if (kt + 2 < NK) STAGE(cur, kt + 2);
    }

    // ---- epilogue: gates + c/h stores only ----
#pragma unroll
    for (int mf = 0; mf < 4; ++mf) {
#pragma unroll
        for (int j = 0; j < 4; ++j) {
            const int rl = wm * 64 + mf * 16 + ((lane >> 4) << 2) + j;
            const int r = row0 + rl;
#pragma unroll
            for (int fc = 0; fc < FG; ++fc) {
                const int cl = wn * CW + fc * 16 + (lane & 15);
                const int c = cb * GW + cl;
                float cv, hv;
                if constexpr (LEAF) {
                    float p0 = acc[mf][0 * FG + fc][j] + bias[c];          // i
                    float p1 = acc[mf][1 * FG + fc][j] + bias[256 + c];    // o
                    float p2 = acc[mf][2 * FG + fc][j] + bias[512 + c];    // u
                    cv = sigf(p0) * tanhf_(p2);
                    hv = sigf(p1) * sigf(cv);   // reference: o * sig(c)
                } else {
                    float p0 = acc[mf][0 * FG + fc][j] + bias[c];           // inp
                    float p1 = acc[mf][1 * FG + fc][j] + bias[256 + c];     // fol
                    float p2 = acc[mf][2 * FG + fc][j] + bias[512 + c];     // for
                    float p3 = acc[mf][3 * FG + fc][j] + bias[768 + c];     // out
                    float p4 = acc[mf][4 * FG + fc][j] + bias[1024 + c];    // upd
                    float lc = cprev[(size_t)r * 512 + c];
                    float rc = cprev[(size_t)r * 512 + 256 + c];
                    cv = sigf(p0) * tanhf_(p4) + sigf(p1) * lc + sigf(p2) * rc;
                    hv = sigf(p3) * tanhf_(cv);
                }
                cout[(size_t)r * 256 + c] = cv;
                hout[(size_t)r * 256 + c] = f2bf(hv);
            }
        }
    }
}

// ================= SMALL kernel (tail levels): 128 rows, 4 waves ==========
template <int NG, int K>
__global__ __launch_bounds__(256, 3) void gemm_small(
    const unsigned short* __restrict__ A,
    const unsigned short* __restrict__ BT,
    const float* __restrict__ bias,
    const float* __restrict__ cprev,
    float* __restrict__ cout,
    unsigned short* __restrict__ hout)
{
    constexpr int CS  = 32;
    constexpr int BN  = NG * CS;
    constexpr int NK  = K / 64;
    constexpr int NBW = BN / 32;
    constexpr int ABUF = 128 * 128;

    __shared__ char smem[2 * ABUF + BN * 128];
    char* Bs = smem + 2 * ABUF;

    const int t = threadIdx.x;
    const int lane = t & 63;
    const int w = t >> 6;
    const int wm = w >> 1, wn = w & 1;
    const int cb = blockIdx.x;
    const int row0 = blockIdx.y * 128;

    const int l3 = lane >> 3;
    const unsigned int swsrc = (unsigned int)(((lane & 7) ^ l3) * 16);
    unsigned int a_src[4];
    unsigned int b_src[NBW];
#pragma unroll
    for (int q = 0; q < 4; ++q)
        a_src[q] = (unsigned int)(row0 + (w * 4 + q) * 8 + l3) * (K * 2) + swsrc;
#pragma unroll
    for (int q = 0; q < NBW; ++q)
        b_src[q] = (unsigned int)(cb * BN + (w * NBW + q) * 8 + l3) * (K * 2) + swsrc;

    const int swz0 = ((lane >> 4) ^ (lane & 7)) * 16;
    const int swz1 = (((lane >> 4) + 4) ^ (lane & 7)) * 16;
    const int aoff = (wm * 64 + (lane & 15)) * 128;
    const int boff = (wn * 16 + (lane & 15)) * 128;

    f32x4 acc[4][NG] = {};

    auto STAGE_A = [&](int buf, int kt) {
        char* As = smem + buf * ABUF;
        const unsigned int k0b = (unsigned int)kt * 128;
#pragma unroll
        for (int q = 0; q < 4; ++q)
            gload_lds16((const char*)A + (size_t)(a_src[q] + k0b),
                        As + (w * 4 + q) * 1024);
    };
    auto STAGE_B = [&](int kt) {
        const unsigned int k0b = (unsigned int)kt * 128;
#pragma unroll
        for (int q = 0; q < NBW; ++q)
            gload_lds16((const char*)BT + (size_t)(b_src[q] + k0b),
                        Bs + (w * NBW + q) * 1024);
    };

    STAGE_A(0, 0);
    STAGE_B(0);
    asm volatile("s_waitcnt vmcnt(0)" ::: "memory");
    __builtin_amdgcn_s_barrier();
    asm volatile("" ::: "memory");

#pragma unroll
    for (int kt = 0; kt < NK; ++kt) {
        const int cur = kt & 1;
        if (kt + 1 < NK) STAGE_A(cur ^ 1, kt + 1);
        const char* As = smem + cur * ABUF;
#pragma unroll
        for (int ks = 0; ks < 2; ++ks) {
            const int sw = ks ? swz1 : swz0;
            short8 a[4];
#pragma unroll
            for (int mf = 0; mf < 4; ++mf)
                a[mf] = *(const short8*)(As + aoff + mf * 2048 + sw);
#pragma unroll
            for (int g = 0; g < NG; ++g) {
                short8 b = *(const short8*)(Bs + g * (CS * 128) + boff + sw);
#pragma unroll
                for (int mf = 0; mf < 4; ++mf)
                    acc[mf][g] = __builtin_amdgcn_mfma_f32_16x16x32_bf16(
                        a[mf], b, acc[mf][g], 0, 0, 0);
            }
        }
        asm volatile("" ::: "memory");
        __builtin_amdgcn_s_barrier();
        asm volatile("" ::: "memory");
        if (kt + 1 < NK) {
            STAGE_B(kt + 1);
            asm volatile("s_waitcnt vmcnt(0)" ::: "memory");
        }
        __builtin_amdgcn_s_barrier();
        asm volatile("" ::: "memory");
    }

#pragma unroll
    for (int mf = 0; mf < 4; ++mf) {
#pragma unroll
        for (int j = 0; j < 4; ++j) {
            const int rl = wm * 64 + mf * 16 + ((lane >> 4) << 2) + j;
            const int r = row0 + rl;
            const int cl = wn * 16 + (lane & 15);
            const int c = cb * 32 + cl;
            float p0 = acc[mf][0][j] + bias[c];
            float p1 = acc[mf][1][j] + bias[256 + c];
            float p2 = acc[mf][2][j] + bias[512 + c];
            float p3 = acc[mf][3][j] + bias[768 + c];
            float p4 = acc[mf][4][j] + bias[1024 + c];
            float lc = cprev[(size_t)r * 512 + c];
            float rc = cprev[(size_t)r * 512 + 256 + c];
            float cv = sigf(p0) * tanhf_(p4) + sigf(p1) * lc + sigf(p2) * rc;
            float hv = sigf(p3) * tanhf_(cv);
            cout[(size_t)r * 256 + c] = cv;
            hout[(size_t)r * 256 + c] = f2bf(hv);
        }
    }
}

// ================= logits over ALL levels: W in registers =================
// 16 lanes per row; each lane covers cols [part*16, part*16+16).
// W slice (80 floats) preloaded into registers, statically indexed.
__global__ __launch_bounds__(256) void logits_all(
    const unsigned short* __restrict__ hA,
    const unsigned short* __restrict__ hRest,
    const float* __restrict__ W_out, const float* __restrict__ b_out,
    float* __restrict__ out)
{
    const int t = threadIdx.x;
    const int part = t & 15;
    const int rl = t >> 4;

    float wreg[80];
#pragma unroll
    for (int e = 0; e < 16; ++e)
#pragma unroll
        for (int cls = 0; cls < 5; ++cls)
            wreg[e * 5 + cls] = W_out[(part * 16 + e) * 5 + cls];
    const float b0 = b_out[0], b1 = b_out[1], b2 = b_out[2],
                b3 = b_out[3], b4 = b_out[4];

    for (int ch = blockIdx.x; ch < 16352; ch += gridDim.x) {
        const int R = ch * 16 + rl;   // [0, 261632)
        const unsigned short* h = (R < 131072)
            ? hA + (size_t)R * HID
            : hRest + (size_t)(R - 131072) * HID;

        short8 h0 = *(const short8*)(h + part * 16);
        short8 h1 = *(const short8*)(h + part * 16 + 8);
        float a0 = 0.f, a1 = 0.f, a2 = 0.f, a3 = 0.f, a4 = 0.f;
#pragma unroll
        for (int e = 0; e < 8; ++e) {
            float f = bf2f((unsigned short)h0[e]);
            a0 = fmaf(f, wreg[e * 5 + 0], a0);
            a1 = fmaf(f, wreg[e * 5 + 1], a1);
            a2 = fmaf(f, wreg[e * 5 + 2], a2);
            a3 = fmaf(f, wreg[e * 5 + 3], a3);
            a4 = fmaf(f, wreg[e * 5 + 4], a4);
        }
#pragma unroll
        for (int e = 0; e < 8; ++e) {
            float f = bf2f((unsigned short)h1[e]);
            a0 = fmaf(f, wreg[(8 + e) * 5 + 0], a0);
            a1 = fmaf(f, wreg[(8 + e) * 5 + 1], a1);
            a2 = fmaf(f, wreg[(8 + e) * 5 + 2], a2);
            a3 = fmaf(f, wreg[(8 + e) * 5 + 3], a3);
            a4 = fmaf(f, wreg[(8 + e) * 5 + 4], a4);
        }
#pragma unroll
        for (int m = 8; m >= 1; m >>= 1) {
            a0 += __shfl_xor(a0, m);
            a1 += __shfl_xor(a1, m);
            a2 += __shfl_xor(a2, m);
            a3 += __shfl_xor(a3, m);
            a4 += __shfl_xor(a4, m);
        }
        if (part == 0) {
            unsigned int V = 262144u - (unsigned int)R;
            int lev = 17 - (31 - __clz(V - 1));
            int start = 262144 - (1 << (18 - lev));
            int local = R - start;
            int nb = 8 - lev;
            int b = local >> nb, j = local & ((1 << nb) - 1);
            int off = 512 - (1 << (9 - lev));
            size_t o = ((size_t)b * 511 + off + j) * 5;
            out[o + 0] = a0 + b0;
            out[o + 1] = a1 + b1;
            out[o + 2] = a2 + b2;
            out[o + 3] = a3 + b3;
            out[o + 4] = a4 + b4;
        }
    }
}

// ================= weight prep =================
__global__ __launch_bounds__(256) void prep_weights(
    const float* __restrict__ W_leaf, const float* __restrict__ W_nl,
    const float* __restrict__ b_nl,
    unsigned short* __restrict__ BleafT,   // leaf: colp = cb*192 + g*64 + cl(64)
    unsigned short* __restrict__ BlevT,    // level: colp = cb*160 + g*32 + cl(32)
    float* __restrict__ bb)
{
    const int T1 = 768 * 320, T2 = 1280 * 512, T3 = 5 * 256;
    for (int idx = blockIdx.x * 256 + threadIdx.x; idx < T1 + T2 + T3;
         idx += gridDim.x * 256) {
        if (idx < T1) {
            int colp = idx / 320, k = idx % 320;
            int cbv = colp / 192, rem = colp % 192;
            int g = rem >> 6, cl = rem & 63;
            int c = cbv * 64 + cl;
            float v = (k < 300) ? W_leaf[((size_t)g * 300 + k) * 256 + c] : 0.0f;
            BleafT[(size_t)colp * 320 + k] = f2bf(v);
        } else if (idx < T1 + T2) {
            int i2 = idx - T1;
            int colp = i2 / 512, k = i2 % 512;
            int cb8 = colp / 160, rem = colp % 160;
            int g = rem >> 5, cl = rem & 31;
            int c = cb8 * 32 + cl;
            float v = W_nl[((size_t)(2 * g + (k >= 256)) * 256 + (k & 255)) * 256 + c];
            BlevT[(size_t)colp * 512 + k] = f2bf(v);
        } else {
            int i3 = idx - T1 - T2;  // g*256 + c
            bb[i3] = b_nl[(size_t)(i3 >> 8) * 512 + (i3 & 255)] +
                     b_nl[(size_t)(i3 >> 8) * 512 + 256 + (i3 & 255)];
        }
    }
}

// ================= emb -> bf16, pad 300 -> 320 =================
__global__ __launch_bounds__(256) void emb_to_bf16(
    const float* __restrict__ emb, unsigned short* __restrict__ embB)
{
    const int total = 131072 * 80;
    for (int idx = blockIdx.x * 256 + threadIdx.x; idx < total;
         idx += gridDim.x * 256) {
        int r = idx / 80, q = idx % 80;
        ushort4v o;
        if (q < 75) {
            const float4 v = *(const float4*)(emb + (size_t)r * 300 + q * 4);
            o.x = f2bf(v.x); o.y = f2bf(v.y); o.z = f2bf(v.z); o.w = f2bf(v.w);
        } else {
            o.x = 0; o.y = 0; o.z = 0; o.w = 0;
        }
        *(ushort4v*)(embB + (size_t)r * 320 + q * 4) = o;
    }
}

extern "C" void kernel_launch(void* const* d_in, const int* in_sizes, int n_in,
                              void* d_out, int out_size, void* d_ws, size_t ws_size,
                              hipStream_t stream) {
    const float* emb    = (const float*)d_in[0];
    const float* W_leaf = (const float*)d_in[1];
    const float* b_leaf = (const float*)d_in[2];
    const float* W_nl   = (const float*)d_in[3];
    const float* b_nl   = (const float*)d_in[4];
    const float* W_out  = (const float*)d_in[5];
    const float* b_out  = (const float*)d_in[6];
    float* out = (float*)d_out;

    // workspace layout (bytes)
    char* ws = (char*)d_ws;
    unsigned short* embB   = (unsigned short*)(ws);              // 83,886,080
    unsigned short* hRest  = (unsigned short*)(ws);              // reuses embB after leaf
    unsigned short* BleafT = (unsigned short*)(ws + 83886080);   //    491,520
    unsigned short* BlevT  = (unsigned short*)(ws + 84377600);   //  1,310,720
    float*          bb     = (float*)(ws + 85688320);            //      5,120
    float*          cA     = (float*)(ws + 85693440);            // 134,217,728
    unsigned short* hA     = (unsigned short*)(ws + 219911168);  //  67,108,864
    float*          cB     = (float*)(ws + 287020032);           //  67,108,864

    prep_weights<<<1024, 256, 0, stream>>>(W_leaf, W_nl, b_nl, BleafT, BlevT, bb);
    emb_to_bf16<<<2048, 256, 0, stream>>>(emb, embB);

    // leaf: M = 131072, NG=3 FG=2 (GW=64), NCB=4, 1D grid 4096 blocks
    gemm_mid<3, 2, 4, 320, true><<<4096, 256, 0, stream>>>(
        embB, BleafT, b_leaf, nullptr, cA, hA);

    const unsigned short* hp = hA;
    const float* cp = cA;
    size_t hoff = 0;
    for (int lev = 1; lev <= 8; ++lev) {
        int n = 1 << (8 - lev);
        int M = 512 * n;
        float* cd = (lev & 1) ? cB : cA;
        unsigned short* hd = hRest + hoff;   // embB region (dead after leaf)
        if (M >= 16384) {
            gemm_mid<5, 1, 8, 512, false><<<(M / 128) * 8, 256, 0, stream>>>(
                hp, BlevT, bb, cp, cd, hd);
        } else {
            gemm_small<5, 512><<<dim3(8, M / 128), 256, 0, stream>>>(
                hp, BlevT, bb, cp, cd, hd);
        }
        cp = cd;
        hp = hd;
        hoff += (size_t)M * HID;
    }

    // final logits over all 261632 rows, grid-stride
    logits_all<<<2048, 256, 0, stream>>>(hA, hRest, W_out, b_out, out);
}